// Round 3
// baseline (16135.207 us; speedup 1.0000x reference)
//
#include <hip/hip_runtime.h>
#include <hip/hip_bf16.h>
#include <stdint.h>

typedef __attribute__((ext_vector_type(8))) short short8;
typedef __attribute__((ext_vector_type(4))) float floatx4;

#define B_ 64
#define T_ 256
#define H_ 1024
#define LATENT_ 256
#define P_ 128
#define RING_ 8   // h2 ring slots (output projection every RING_ steps)

__device__ __forceinline__ float sigmoidf_(float x) {
    return 1.0f / (1.0f + __expf(-x));
}
__device__ __forceinline__ float tanh_fast(float x) {
    float e = __expf(2.0f * x);
    return 1.0f - 2.0f / (e + 1.0f);
}

// ---------------------------------------------------------------------------
// fp32 -> bf16 conversion, 4 elements/thread. n must be a multiple of 4.
// ---------------------------------------------------------------------------
__global__ __launch_bounds__(256) void cvt_f2b(
    const float* __restrict__ src, __hip_bfloat16* __restrict__ dst, int n)
{
    int i = (blockIdx.x * 256 + threadIdx.x) * 4;
    if (i < n) {
        float4 v = *(const float4*)(src + i);
        dst[i + 0] = __float2bfloat16(v.x);
        dst[i + 1] = __float2bfloat16(v.y);
        dst[i + 2] = __float2bfloat16(v.z);
        dst[i + 3] = __float2bfloat16(v.w);
    }
}

// ---------------------------------------------------------------------------
// h0 = z @ fc_init_w^T + fc_init_b  (64x1024, K=256), fp32 in, bf16 out.
// Also zeroes both c buffers. grid 256 x 256 threads, 1 thread/output elem.
// ---------------------------------------------------------------------------
__global__ __launch_bounds__(256) void h0_kernel(
    const float* __restrict__ z,
    const float* __restrict__ fw,
    const float* __restrict__ fb,
    __hip_bfloat16* __restrict__ h0,
    float* __restrict__ czero)   // 2 * 64*1024 floats, zero them
{
    int idx = blockIdx.x * 256 + threadIdx.x;   // 0..65535
    int b = idx >> 10, j = idx & 1023;
    const float* zp = z + b * LATENT_;
    const float* wp = fw + j * LATENT_;
    float acc = fb[j];
    for (int k = 0; k < LATENT_; k += 4) {
        float4 zv = *(const float4*)(zp + k);
        float4 wv = *(const float4*)(wp + k);
        acc += zv.x * wv.x + zv.y * wv.y + zv.z * wv.z + zv.w * wv.w;
    }
    h0[idx] = __float2bfloat16(acc);
    czero[idx] = 0.0f;
    czero[idx + B_ * H_] = 0.0f;
}

// ---------------------------------------------------------------------------
// One LSTM timestep, fused gates-GEMM + cell.
//   gates(64 x 4096) = [x_t | h_prev] @ [Wih | Whh]^T   (K = Kx + 1024)
// grid: 64 blocks (16 hidden cols each), 512 threads = 8 waves.
// wave = (gate g in 0..3) x (K-half kh in 0..1).
// Each wave: M=64 (4 m-tiles), N=16, via mfma_f32_16x16x32_bf16.
// Weights/x/hprev are bf16 (pre-converted); biases fp32; c fp32.
// Epilogue: LDS exchange -> LSTM cell -> h (bf16) + c (fp32).
// ---------------------------------------------------------------------------
__global__ __launch_bounds__(512) void lstm_step(
    const __hip_bfloat16* __restrict__ x, long xbs, int Kx,
    const __hip_bfloat16* __restrict__ hprev,
    const __hip_bfloat16* __restrict__ Wih,
    const __hip_bfloat16* __restrict__ Whh,
    const float* __restrict__ bih,
    const float* __restrict__ bhh,
    float* __restrict__ c,
    __hip_bfloat16* __restrict__ hout)
{
    __shared__ float gbuf[8][64][16];   // 32 KB
    const int tid  = threadIdx.x;
    const int w    = tid >> 6;     // wave 0..7
    const int g    = w & 3;        // gate group (i,f,g,o)
    const int kh   = w >> 2;       // K-half
    const int l    = tid & 63;
    const int l15  = l & 15;
    const int quad = l >> 4;       // 0..3
    const int ks   = quad * 8;     // k offset within 32-chunk
    const int jb   = blockIdx.x;   // hidden col group, 16 cols
    const int n    = g * H_ + jb * 16 + l15;   // weight row for B-frag

    floatx4 acc[4] = {};
    const int NC = (Kx + H_) >> 5;           // 32-wide K chunks (36 or 64)
    const int ck0 = kh * (NC >> 1);
    const int ck1 = ck0 + (NC >> 1);
    for (int ck = ck0; ck < ck1; ++ck) {
        int kk = (ck << 5) + ks;
        const short* ap;  long ast;
        const short* wp;
        if (kk < Kx) {
            ap  = (const short*)x + kk;  ast = xbs;
            wp  = (const short*)Wih + (long)n * Kx + kk;
        } else {
            int k2 = kk - Kx;
            ap  = (const short*)hprev + k2;  ast = H_;
            wp  = (const short*)Whh + (long)n * H_ + k2;
        }
        short8 bfrag = *(const short8*)wp;
#pragma unroll
        for (int mt = 0; mt < 4; ++mt) {
            int m = mt * 16 + l15;
            short8 afrag = *(const short8*)(ap + (long)m * ast);
            acc[mt] = __builtin_amdgcn_mfma_f32_16x16x32_bf16(afrag, bfrag, acc[mt], 0, 0, 0);
        }
    }

    // C/D layout: col = lane&15, row = quad*4 + reg
#pragma unroll
    for (int mt = 0; mt < 4; ++mt)
#pragma unroll
        for (int r = 0; r < 4; ++r)
            gbuf[w][mt * 16 + quad * 4 + r][l15] = acc[mt][r];
    __syncthreads();

    // cell: 64x16 = 1024 elems, 512 threads -> 2 each
#pragma unroll
    for (int q = 0; q < 2; ++q) {
        int e = tid + q * 512;
        int row = e >> 4, col = e & 15;   // row = batch index
        int j = jb * 16 + col;
        float iv = gbuf[0][row][col] + gbuf[4][row][col] + bih[0 * H_ + j] + bhh[0 * H_ + j];
        float fv = gbuf[1][row][col] + gbuf[5][row][col] + bih[1 * H_ + j] + bhh[1 * H_ + j];
        float gv = gbuf[2][row][col] + gbuf[6][row][col] + bih[2 * H_ + j] + bhh[2 * H_ + j];
        float ov = gbuf[3][row][col] + gbuf[7][row][col] + bih[3 * H_ + j] + bhh[3 * H_ + j];
        int ci = row * H_ + j;
        float cv = c[ci];
        float cn = sigmoidf_(fv) * cv + sigmoidf_(iv) * tanh_fast(gv);
        float hv = sigmoidf_(ov) * tanh_fast(cn);
        c[ci] = cn;
        hout[ci] = __float2bfloat16(hv);
    }
}

// ---------------------------------------------------------------------------
// Output projection for a chunk of RING_ timesteps held in the h2 ring:
//   out[:, t0+s, :] = sigmoid(ring[s] @ out_w^T + out_b),  s in [0, RING_)
// ring is (RING_*B, H) bf16 row-major. out_w bf16, out_b fp32, out fp32.
// grid (8, 8), 256 threads = 4 waves; each wave 16(M) x 16(N), K=1024.
// ---------------------------------------------------------------------------
__global__ __launch_bounds__(256) void out_gemm_chunk(
    const __hip_bfloat16* __restrict__ ring,  // (RING_*B, H)
    const __hip_bfloat16* __restrict__ ow,    // (P, H) bf16
    const float* __restrict__ ob,             // (P) fp32
    float* __restrict__ out,                  // (B, T, P) fp32
    int t0)
{
    const int tid = threadIdx.x;
    const int w = tid >> 6, l = tid & 63;
    const int l15 = l & 15, quad = l >> 4, ks = quad * 8;
    const int mBase = blockIdx.x * 64 + w * 16;   // row in ring, < 512
    const int p0 = blockIdx.y * 16;

    const short* A  = (const short*)ring + (long)(mBase + l15) * H_ + ks;
    const short* Bp = (const short*)ow + (long)(p0 + l15) * H_ + ks;
    floatx4 acc = {};
    for (int k = 0; k < H_; k += 32) {
        short8 a = *(const short8*)(A + k);
        short8 b = *(const short8*)(Bp + k);
        acc = __builtin_amdgcn_mfma_f32_16x16x32_bf16(a, b, acc, 0, 0, 0);
    }
    int p = p0 + l15;
    float bias = ob[p];
#pragma unroll
    for (int r = 0; r < 4; ++r) {
        int m = mBase + quad * 4 + r;     // m = slot*64 + b
        int s = m >> 6, b = m & 63;
        int t = t0 + s;
        float v = sigmoidf_(acc[r] + bias);
        out[(long)b * (T_ * P_) + t * P_ + p] = v;
    }
}

// ---------------------------------------------------------------------------
extern "C" void kernel_launch(void* const* d_in, const int* in_sizes, int n_in,
                              void* d_out, int out_size, void* d_ws, size_t ws_size,
                              hipStream_t stream) {
    // All inputs are fp32 per the reference (reading them as bf16 was the
    // R0/R1 NaN source: fp32 mantissa halves decode as bf16 NaN ~2^-9/elem).
    const float* z    = (const float*)d_in[0];
    const float* tseq = (const float*)d_in[1];
    const float* fw   = (const float*)d_in[2];
    const float* fb   = (const float*)d_in[3];
    const float* stok = (const float*)d_in[4];
    const float* Wih0 = (const float*)d_in[5];
    const float* Whh0 = (const float*)d_in[6];
    const float* bih0 = (const float*)d_in[7];
    const float* bhh0 = (const float*)d_in[8];
    const float* Wih1 = (const float*)d_in[9];
    const float* Whh1 = (const float*)d_in[10];
    const float* bih1 = (const float*)d_in[11];
    const float* bhh1 = (const float*)d_in[12];
    const float* ow   = (const float*)d_in[13];
    const float* ob   = (const float*)d_in[14];
    float* out = (float*)d_out;

    // Workspace layout (~31.1 MB): bf16 copies of weights + sequence inputs,
    // small recurrent state buffers, fp32 cell state.
    const int BH = B_ * H_;
    char* ws = (char*)d_ws;
    size_t off = 0;
    __hip_bfloat16* Wih0b = (__hip_bfloat16*)(ws + off); off += (size_t)4 * H_ * P_ * 2;      // 1 MB
    __hip_bfloat16* Whh0b = (__hip_bfloat16*)(ws + off); off += (size_t)4 * H_ * H_ * 2;      // 8 MB
    __hip_bfloat16* Wih1b = (__hip_bfloat16*)(ws + off); off += (size_t)4 * H_ * H_ * 2;      // 8 MB
    __hip_bfloat16* Whh1b = (__hip_bfloat16*)(ws + off); off += (size_t)4 * H_ * H_ * 2;      // 8 MB
    __hip_bfloat16* owb   = (__hip_bfloat16*)(ws + off); off += (size_t)P_ * H_ * 2;          // 256 KB
    __hip_bfloat16* tseqb = (__hip_bfloat16*)(ws + off); off += (size_t)B_ * T_ * P_ * 2;     // 4 MB
    __hip_bfloat16* stokb = (__hip_bfloat16*)(ws + off); off += 256;                          // 128 elems
    __hip_bfloat16* h1pp  = (__hip_bfloat16*)(ws + off); off += (size_t)2 * BH * 2;           // 256 KB
    __hip_bfloat16* h2ring= (__hip_bfloat16*)(ws + off); off += (size_t)RING_ * BH * 2;       // 1 MB
    __hip_bfloat16* h0    = (__hip_bfloat16*)(ws + off); off += (size_t)BH * 2;               // 128 KB
    float* cbuf           = (float*)(ws + off);          off += (size_t)2 * BH * 4;           // 512 KB
    float* c0 = cbuf;
    float* c1 = cbuf + BH;

    // One-time fp32 -> bf16 conversions (serialized on stream before use).
    auto cvt = [&](const float* s, __hip_bfloat16* d, int n) {
        hipLaunchKernelGGL(cvt_f2b, dim3((n / 4 + 255) / 256), dim3(256), 0, stream, s, d, n);
    };
    cvt(Wih0, Wih0b, 4 * H_ * P_);
    cvt(Whh0, Whh0b, 4 * H_ * H_);
    cvt(Wih1, Wih1b, 4 * H_ * H_);
    cvt(Whh1, Whh1b, 4 * H_ * H_);
    cvt(ow,   owb,   P_ * H_);
    cvt(tseq, tseqb, B_ * T_ * P_);
    cvt(stok, stokb, P_);

    hipLaunchKernelGGL(h0_kernel, dim3(256), dim3(256), 0, stream, z, fw, fb, h0, cbuf);

    for (int t = 0; t < T_; ++t) {
        // ---- layer 0 step t ----
        const __hip_bfloat16* x;
        long xbs;
        if (t == 0) { x = stokb; xbs = 0; }
        else        { x = tseqb + (long)(t - 1) * P_; xbs = (long)T_ * P_; }
        const __hip_bfloat16* hp0 = (t == 0) ? h0 : (h1pp + (long)((t - 1) & 1) * BH);
        __hip_bfloat16* h1out = h1pp + (long)(t & 1) * BH;
        hipLaunchKernelGGL(lstm_step, dim3(64), dim3(512), 0, stream,
                           x, xbs, P_, hp0, Wih0b, Whh0b, bih0, bhh0, c0, h1out);

        // ---- layer 1 step t ----
        const __hip_bfloat16* hp1 = (t == 0) ? h0 : (h2ring + (long)((t - 1) % RING_) * BH);
        __hip_bfloat16* h2out = h2ring + (long)(t % RING_) * BH;
        hipLaunchKernelGGL(lstm_step, dim3(64), dim3(512), 0, stream,
                           h1out, (long)H_, H_, hp1, Wih1b, Whh1b, bih1, bhh1, c1, h2out);

        // ---- output projection for the completed ring chunk ----
        if ((t % RING_) == RING_ - 1) {
            int t0 = t - (RING_ - 1);
            hipLaunchKernelGGL(out_gemm_chunk, dim3(RING_, 8), dim3(256), 0, stream,
                               h2ring, owb, ob, out, t0);
        }
    }
}